// Round 3
// baseline (334.142 us; speedup 1.0000x reference)
//
#include <hip/hip_runtime.h>
#include <hip/hip_bf16.h>

// Problem constants
#define Bb 8
#define Ss 8192
#define Dd 256            // DIN == DH == 256
#define Mm (Bb * Ss)      // 65536 rows
#define Nn 512            // 2*DH output cols of the GEMM
#define NCHUNK 128
#define CLEN (Ss / NCHUNK) // 64

typedef __hip_bfloat16 bf16;
typedef __attribute__((ext_vector_type(8))) short short8;
typedef __attribute__((ext_vector_type(4))) float f32x4;

__device__ __forceinline__ void load_lds16(const void* g, void* l) {
  __builtin_amdgcn_global_load_lds(
      (const __attribute__((address_space(1))) void*)g,
      (__attribute__((address_space(3))) void*)l, 16, 0, 0);
}

// ---------------------------------------------------------------------------
// f32 -> bf16 convert (vectorized float4 -> 4x bf16)
// ---------------------------------------------------------------------------
__global__ __launch_bounds__(256) void cvt_f32_bf16(const float* __restrict__ in,
                                                    bf16* __restrict__ out,
                                                    long n4) {
  long i = (long)blockIdx.x * blockDim.x + threadIdx.x;
  if (i >= n4) return;
  const float4 v = ((const float4*)in)[i];
  union { ushort4 u; bf16 h[4]; } o;
  o.h[0] = __float2bfloat16(v.x);
  o.h[1] = __float2bfloat16(v.y);
  o.h[2] = __float2bfloat16(v.z);
  o.h[3] = __float2bfloat16(v.w);
  ((ushort4*)out)[i] = o.u;
}

// ---------------------------------------------------------------------------
// GEMM: GH[m, n] = sum_k X[m, k] * W[n, k]   (bias added later in scan passes)
// X: (Mm, 256) bf16 row-major; W: (512, 256) bf16 row-major (B^T layout)
// Block tile 128x128, BK=32, 256 threads (4 waves, each wave 64x64).
// ---------------------------------------------------------------------------
__global__ __launch_bounds__(256) void gemm_gh(const bf16* __restrict__ X,
                                               const bf16* __restrict__ W,
                                               bf16* __restrict__ GH) {
  __shared__ __align__(16) bf16 As[128 * 32];
  __shared__ __align__(16) bf16 Bs[128 * 32];

  const int tid = threadIdx.x;
  const int w = tid >> 6;        // wave 0..3
  const int l = tid & 63;        // lane
  const int fl = l & 15;         // row/col within 16
  const int q = l >> 4;          // quad 0..3

  const long rowBase = (long)blockIdx.x * 128;
  const int colBase = blockIdx.y * 128;

  const int wrow = (w >> 1) * 64;
  const int wcol = (w & 1) * 64;

  // staging: thread tid covers tile bytes [tid*16, tid*16+16) per 4KB half
  const int sr = tid >> 2;        // 0..63 row within half
  const int sc = (tid & 3) * 8;   // col 0/8/16/24

  f32x4 acc[4][4];
#pragma unroll
  for (int i = 0; i < 4; i++)
#pragma unroll
    for (int j = 0; j < 4; j++) acc[i][j] = (f32x4)0.0f;

  for (int k0 = 0; k0 < 256; k0 += 32) {
    __syncthreads();  // previous iter's ds_reads done before overwrite
    load_lds16(X + (rowBase + sr) * 256 + k0 + sc, &As[(long)w * 512]);
    load_lds16(X + (rowBase + 64 + sr) * 256 + k0 + sc, &As[2048 + (long)w * 512]);
    load_lds16(W + (colBase + sr) * 256 + k0 + sc, &Bs[(long)w * 512]);
    load_lds16(W + (colBase + 64 + sr) * 256 + k0 + sc, &Bs[2048 + (long)w * 512]);
    __syncthreads();  // compiler drains vmcnt before s_barrier

    short8 af[4], bfr[4];
#pragma unroll
    for (int mt = 0; mt < 4; mt++)
      af[mt] = *(const short8*)&As[(wrow + 16 * mt + fl) * 32 + q * 8];
#pragma unroll
    for (int nt = 0; nt < 4; nt++)
      bfr[nt] = *(const short8*)&Bs[(wcol + 16 * nt + fl) * 32 + q * 8];

#pragma unroll
    for (int mt = 0; mt < 4; mt++)
#pragma unroll
      for (int nt = 0; nt < 4; nt++)
        acc[mt][nt] = __builtin_amdgcn_mfma_f32_16x16x32_bf16(
            af[mt], bfr[nt], acc[mt][nt], 0, 0, 0);
  }

  // Epilogue: C/D layout col = lane&15, row = quad*4 + reg
#pragma unroll
  for (int mt = 0; mt < 4; mt++) {
#pragma unroll
    for (int nt = 0; nt < 4; nt++) {
      const long gcol = colBase + wcol + 16 * nt + fl;
      const long r0 = rowBase + wrow + 16 * mt + q * 4;
#pragma unroll
      for (int r = 0; r < 4; r++)
        GH[(r0 + r) * Nn + gcol] = __float2bfloat16(acc[mt][nt][r]);
    }
  }
}

// ---------------------------------------------------------------------------
// Pointwise: a = sigmoid(-gate), v = sigmoid(gate) * g(hidden)
// ---------------------------------------------------------------------------
__device__ __forceinline__ void av_from_gh(float gate, float hid, float& a,
                                           float& v) {
  gate = fminf(fmaxf(gate, -20.f), 20.f);
  float eg = __expf(gate);
  a = 1.f / (1.f + eg);   // sigmoid(-gate) = 1 - z
  float z = eg * a;       // sigmoid(gate)
  float gfun;
  if (hid >= 0.f) {
    gfun = hid + 0.5f;
  } else {
    float eh = __expf(fmaxf(hid, -20.f));
    gfun = eh / (1.f + eh);  // sigmoid(hid)
  }
  v = z * gfun;
}

// Pass A: per-chunk summaries. block = (b, c); thread = channel d.
__global__ __launch_bounds__(256) void scan_partial(
    const bf16* __restrict__ GH, const float* __restrict__ bias,
    float* __restrict__ Asum, float* __restrict__ Vsum) {
  const int d = threadIdx.x;
  const int c = blockIdx.x % NCHUNK;
  const int b = blockIdx.x / NCHUNK;
  const float bg = bias[d];
  const float bh = bias[d + 256];
  float A = 1.f, H = 0.f;
  long base = ((long)b * Ss + (long)c * CLEN) * Nn + d;
#pragma unroll 4
  for (int t = 0; t < CLEN; t++) {
    float gate = __bfloat162float(GH[base]) + bg;
    float hid = __bfloat162float(GH[base + 256]) + bh;
    float a, v;
    av_from_gh(gate, hid, a, v);
    A *= a;
    H = a * H + v;
    base += Nn;
  }
  Asum[(long)blockIdx.x * 256 + d] = A;
  Vsum[(long)blockIdx.x * 256 + d] = H;
}

// Pass B: sequential combine across chunks. block = b; thread = d.
__global__ __launch_bounds__(256) void scan_combine(
    const float* __restrict__ Asum, const float* __restrict__ Vsum,
    float* __restrict__ Hin) {
  const int d = threadIdx.x;
  const int b = blockIdx.x;
  float h = 0.5f;  // h0 = g(0) = 0.5
#pragma unroll 4
  for (int c = 0; c < NCHUNK; c++) {
    const long i = ((long)b * NCHUNK + c) * 256 + d;
    Hin[i] = h;
    h = Asum[i] * h + Vsum[i];
  }
}

// Pass C: final scan. WRITE_BF16 ? write bf16 hidden stream (layer-0 -> X1)
//                                : write f32 hidden stream (layer-1 -> out)
// Always writes last-step h as f32.
template <bool WRITE_BF16>
__global__ __launch_bounds__(256) void scan_final(
    const bf16* __restrict__ GH, const float* __restrict__ bias,
    const float* __restrict__ Hin, bf16* __restrict__ OutB,
    float* __restrict__ OutF, float* __restrict__ Hlast) {
  const int d = threadIdx.x;
  const int c = blockIdx.x % NCHUNK;
  const int b = blockIdx.x / NCHUNK;
  const float bg = bias[d];
  const float bh = bias[d + 256];
  float h = Hin[(long)blockIdx.x * 256 + d];
  long base = ((long)b * Ss + (long)c * CLEN) * Nn + d;
  long obase = ((long)b * Ss + (long)c * CLEN) * 256 + d;
#pragma unroll 4
  for (int t = 0; t < CLEN; t++) {
    float gate = __bfloat162float(GH[base]) + bg;
    float hid = __bfloat162float(GH[base + 256]) + bh;
    float a, v;
    av_from_gh(gate, hid, a, v);
    h = a * h + v;
    if (WRITE_BF16)
      OutB[obase] = __float2bfloat16(h);
    else
      OutF[obase] = h;
    base += Nn;
    obase += 256;
  }
  if (c == NCHUNK - 1) Hlast[b * 256 + d] = h;
}

// ---------------------------------------------------------------------------
extern "C" void kernel_launch(void* const* d_in, const int* in_sizes, int n_in,
                              void* d_out, int out_size, void* d_ws,
                              size_t ws_size, hipStream_t stream) {
  const float* x = (const float*)d_in[0];
  const float* W0f = (const float*)d_in[1];
  const float* b0 = (const float*)d_in[2];
  const float* W1f = (const float*)d_in[3];
  const float* b1 = (const float*)d_in[4];

  float* outF = (float*)d_out;              // out1 (f32), Mm*256 elements
  float* hlast = outF + (long)Mm * 256;     // h: (2, 8, 1, 256) f32
  // d_out's first 32 MiB doubles as bf16 scratch for x / X1 (dead before the
  // final f32 out-write overwrites it; all ordering is stream-sequential).
  bf16* Xb = (bf16*)d_out;

  char* ws = (char*)d_ws;
  bf16* GH = (bf16*)ws;                              // Mm*512 bf16 = 64 MiB
  bf16* W0b = (bf16*)(ws + (long)Mm * Nn * 2);       // 512*256 bf16 = 256 KiB
  bf16* W1b = W0b + (long)Nn * Dd;
  float* Asum = (float*)(W1b + (long)Nn * Dd);       // 1 MiB each
  float* Vsum = Asum + (long)Bb * NCHUNK * 256;
  float* Hin = Vsum + (long)Bb * NCHUNK * 256;

  const dim3 gemmGrid(Mm / 128, Nn / 128);
  const dim3 blk(256);
  const dim3 scanGrid(Bb * NCHUNK);

  // Convert inputs f32 -> bf16
  {
    const long n4x = (long)Mm * Dd / 4;
    cvt_f32_bf16<<<dim3((n4x + 255) / 256), blk, 0, stream>>>(x, Xb, n4x);
    const long n4w = (long)Nn * Dd / 4;
    cvt_f32_bf16<<<dim3((n4w + 255) / 256), blk, 0, stream>>>(W0f, W0b, n4w);
    cvt_f32_bf16<<<dim3((n4w + 255) / 256), blk, 0, stream>>>(W1f, W1b, n4w);
  }

  // Layer 0
  gemm_gh<<<gemmGrid, blk, 0, stream>>>(Xb, W0b, GH);
  scan_partial<<<scanGrid, blk, 0, stream>>>(GH, b0, Asum, Vsum);
  scan_combine<<<dim3(Bb), blk, 0, stream>>>(Asum, Vsum, Hin);
  // X1 (bf16) overwrites the x scratch; hlast0 is f32 at its final location.
  scan_final<true><<<scanGrid, blk, 0, stream>>>(GH, b0, Hin, Xb, nullptr,
                                                 hlast);

  // Layer 1
  gemm_gh<<<gemmGrid, blk, 0, stream>>>(Xb, W1b, GH);
  scan_partial<<<scanGrid, blk, 0, stream>>>(GH, b1, Asum, Vsum);
  scan_combine<<<dim3(Bb), blk, 0, stream>>>(Asum, Vsum, Hin);
  // Final f32 output overwrites the dead X1 scratch region.
  scan_final<false><<<scanGrid, blk, 0, stream>>>(GH, b1, Hin, nullptr, outF,
                                                  hlast + Bb * 256);
}

// Round 4
// 279.828 us; speedup vs baseline: 1.1941x; 1.1941x over previous
//
#include <hip/hip_runtime.h>
#include <hip/hip_bf16.h>

// Problem constants
#define Bb 8
#define Ss 8192
#define Dd 256             // DIN == DH == 256
#define Mm (Bb * Ss)       // 65536 rows
#define Nn 512             // 2*DH output cols of the GEMM
#define NCHUNK 128
#define CLEN (Ss / NCHUNK) // 64

typedef __hip_bfloat16 bf16;
typedef __attribute__((ext_vector_type(8))) short short8;
typedef __attribute__((ext_vector_type(4))) float f32x4;

__device__ __forceinline__ void load_lds16(const void* g, void* l) {
  __builtin_amdgcn_global_load_lds(
      (const __attribute__((address_space(1))) void*)g,
      (__attribute__((address_space(3))) void*)l, 16, 0, 0);
}

// ---------------------------------------------------------------------------
// f32 -> bf16 convert (vectorized float4 -> 4x bf16)
// ---------------------------------------------------------------------------
__global__ __launch_bounds__(256) void cvt_f32_bf16(const float* __restrict__ in,
                                                    bf16* __restrict__ out,
                                                    long n4) {
  long i = (long)blockIdx.x * blockDim.x + threadIdx.x;
  if (i >= n4) return;
  const float4 v = ((const float4*)in)[i];
  union { ushort4 u; bf16 h[4]; } o;
  o.h[0] = __float2bfloat16(v.x);
  o.h[1] = __float2bfloat16(v.y);
  o.h[2] = __float2bfloat16(v.z);
  o.h[3] = __float2bfloat16(v.w);
  ((ushort4*)out)[i] = o.u;
}

// ---------------------------------------------------------------------------
// Pointwise: a = sigmoid(-gate), v = sigmoid(gate) * g(hidden)
// ---------------------------------------------------------------------------
__device__ __forceinline__ void av_from_gh(float gate, float hid, float& a,
                                           float& v) {
  gate = fminf(fmaxf(gate, -20.f), 20.f);
  float eg = __expf(gate);
  a = 1.f / (1.f + eg);   // sigmoid(-gate) = 1 - z
  float z = eg * a;       // sigmoid(gate)
  float gfun;
  if (hid >= 0.f) {
    gfun = hid + 0.5f;
  } else {
    float eh = __expf(fmaxf(hid, -20.f));
    gfun = eh / (1.f + eh);  // sigmoid(hid)
  }
  v = z * gfun;
}

__device__ __forceinline__ unsigned pack_av(float a, float v) {
  union { bf16 h[2]; unsigned u; } o;
  o.h[0] = __float2bfloat16(a);
  o.h[1] = __float2bfloat16(v);
  return o.u;
}

// ---------------------------------------------------------------------------
// Fused GEMM + bias + pointwise. Paired-column tiling:
//   block (bx, cb): rows [bx*128, +128), paired channels d in [cb*64, +64)
//   n-tiles 0,1 = gate cols d (W rows d); n-tiles 2,3 = hidden cols d+256.
// Writes AV[m*256 + d] = pack(a, v) as bf16x2 in uint32.
// X: (Mm,256) bf16 row-major; W: (512,256) bf16 row-major; bias: (512) f32.
// ---------------------------------------------------------------------------
__global__ __launch_bounds__(256) void gemm_av(const bf16* __restrict__ X,
                                               const bf16* __restrict__ W,
                                               const float* __restrict__ bias,
                                               unsigned* __restrict__ AV) {
  __shared__ __align__(16) bf16 As[128 * 32];
  __shared__ __align__(16) bf16 Bs[128 * 32];

  const int tid = threadIdx.x;
  const int w = tid >> 6;        // wave 0..3
  const int l = tid & 63;        // lane
  const int fl = l & 15;
  const int q = l >> 4;          // quad 0..3

  const long rowBase = (long)blockIdx.x * 128;
  const int cb = blockIdx.y;     // paired-channel block 0..3 (64 channels)

  const int wrow = (w >> 1) * 64;
  const int wc = (w & 1) * 32;   // wave's channel offset within the 64

  const int sr = tid >> 2;       // 0..63
  const int sc = (tid & 3) * 8;

  f32x4 acc[4][4];
#pragma unroll
  for (int i = 0; i < 4; i++)
#pragma unroll
    for (int j = 0; j < 4; j++) acc[i][j] = (f32x4)0.0f;

  for (int k0 = 0; k0 < 256; k0 += 32) {
    __syncthreads();
    // A tile: 128 rows x 32 k
    load_lds16(X + (rowBase + sr) * 256 + k0 + sc, &As[(long)w * 512]);
    load_lds16(X + (rowBase + 64 + sr) * 256 + k0 + sc, &As[2048 + (long)w * 512]);
    // B tile: Bs rows 0..63 = gate W-rows [cb*64, +64); rows 64..127 = hidden
    // W-rows [256+cb*64, +64)
    load_lds16(W + (cb * 64 + sr) * 256 + k0 + sc, &Bs[(long)w * 512]);
    load_lds16(W + (256 + cb * 64 + sr) * 256 + k0 + sc, &Bs[2048 + (long)w * 512]);
    __syncthreads();

    short8 af[4], bfr[4];
#pragma unroll
    for (int mt = 0; mt < 4; mt++)
      af[mt] = *(const short8*)&As[(wrow + 16 * mt + fl) * 32 + q * 8];
    // nt 0,1: gate rows wc+16*nt; nt 2,3: hidden rows 64+wc+16*(nt-2)
#pragma unroll
    for (int nt = 0; nt < 4; nt++) {
      const int brow = (nt < 2) ? (wc + 16 * nt + fl) : (64 + wc + 16 * (nt - 2) + fl);
      bfr[nt] = *(const short8*)&Bs[brow * 32 + q * 8];
    }

#pragma unroll
    for (int mt = 0; mt < 4; mt++)
#pragma unroll
      for (int nt = 0; nt < 4; nt++)
        acc[mt][nt] = __builtin_amdgcn_mfma_f32_16x16x32_bf16(
            af[mt], bfr[nt], acc[mt][nt], 0, 0, 0);
  }

  // Epilogue: lane's acc[mt][p] (gate) pairs with acc[mt][p+2] (hidden),
  // both for channel d = cb*64 + wc + 16*p + fl.
  float bg[2], bh[2];
#pragma unroll
  for (int p = 0; p < 2; p++) {
    const int d = cb * 64 + wc + 16 * p + fl;
    bg[p] = bias[d];
    bh[p] = bias[256 + d];
  }
#pragma unroll
  for (int mt = 0; mt < 4; mt++) {
#pragma unroll
    for (int p = 0; p < 2; p++) {
      const int d = cb * 64 + wc + 16 * p + fl;
      const long r0 = rowBase + wrow + 16 * mt + q * 4;
#pragma unroll
      for (int r = 0; r < 4; r++) {
        float a, v;
        av_from_gh(acc[mt][p][r] + bg[p], acc[mt][p + 2][r] + bh[p], a, v);
        AV[(r0 + r) * 256 + d] = pack_av(a, v);
      }
    }
  }
}

// ---------------------------------------------------------------------------
// Pass A: per-chunk summaries. block = (b, c); thread = channel d.
// ---------------------------------------------------------------------------
__global__ __launch_bounds__(256) void scan_partial(
    const unsigned* __restrict__ AV, float* __restrict__ Asum,
    float* __restrict__ Vsum) {
  const int d = threadIdx.x;
  const int c = blockIdx.x % NCHUNK;
  const int b = blockIdx.x / NCHUNK;
  float A = 1.f, H = 0.f;
  long base = ((long)b * Ss + (long)c * CLEN) * 256 + d;
#pragma unroll 8
  for (int t = 0; t < CLEN; t++) {
    const unsigned p = AV[base];
    const float a = __uint_as_float((p & 0xffffu) << 16);
    const float v = __uint_as_float(p & 0xffff0000u);
    A *= a;
    H = a * H + v;
    base += 256;
  }
  Asum[(long)blockIdx.x * 256 + d] = A;
  Vsum[(long)blockIdx.x * 256 + d] = H;
}

// ---------------------------------------------------------------------------
// Pass B: sequential combine across chunks. block = b; thread = d.
// ---------------------------------------------------------------------------
__global__ __launch_bounds__(256) void scan_combine(
    const float* __restrict__ Asum, const float* __restrict__ Vsum,
    float* __restrict__ Hin) {
  const int d = threadIdx.x;
  const int b = blockIdx.x;
  float h = 0.5f;  // h0 = g(0) = 0.5
#pragma unroll 8
  for (int c = 0; c < NCHUNK; c++) {
    const long i = ((long)b * NCHUNK + c) * 256 + d;
    Hin[i] = h;
    h = Asum[i] * h + Vsum[i];
  }
}

// ---------------------------------------------------------------------------
// Pass C: final scan. WRITE_BF16 ? bf16 hidden stream (layer0 -> X1)
//                                : f32 hidden stream (layer1 -> out)
// ---------------------------------------------------------------------------
template <bool WRITE_BF16>
__global__ __launch_bounds__(256) void scan_final(
    const unsigned* __restrict__ AV, const float* __restrict__ Hin,
    bf16* __restrict__ OutB, float* __restrict__ OutF,
    float* __restrict__ Hlast) {
  const int d = threadIdx.x;
  const int c = blockIdx.x % NCHUNK;
  const int b = blockIdx.x / NCHUNK;
  float h = Hin[(long)blockIdx.x * 256 + d];
  long base = ((long)b * Ss + (long)c * CLEN) * 256 + d;
#pragma unroll 8
  for (int t = 0; t < CLEN; t++) {
    const unsigned p = AV[base];
    const float a = __uint_as_float((p & 0xffffu) << 16);
    const float v = __uint_as_float(p & 0xffff0000u);
    h = a * h + v;
    if (WRITE_BF16)
      OutB[base] = __float2bfloat16(h);
    else
      OutF[base] = h;
    base += 256;
  }
  if (c == NCHUNK - 1) Hlast[b * 256 + d] = h;
}

// ---------------------------------------------------------------------------
extern "C" void kernel_launch(void* const* d_in, const int* in_sizes, int n_in,
                              void* d_out, int out_size, void* d_ws,
                              size_t ws_size, hipStream_t stream) {
  const float* x = (const float*)d_in[0];
  const float* W0f = (const float*)d_in[1];
  const float* b0 = (const float*)d_in[2];
  const float* W1f = (const float*)d_in[3];
  const float* b1 = (const float*)d_in[4];

  float* outF = (float*)d_out;              // out1 (f32), Mm*256 elements
  float* hlast = outF + (long)Mm * 256;     // h: (2,8,1,256) f32
  // d_out's first 32 MiB doubles as bf16 scratch for x / X1 (dead before the
  // final f32 out-write overwrites it; ordering is stream-sequential).
  bf16* Xb = (bf16*)d_out;

  char* ws = (char*)d_ws;
  unsigned* AV = (unsigned*)ws;                      // Mm*256 u32 = 64 MiB
  bf16* W0b = (bf16*)(ws + (long)Mm * 256 * 4);      // 512*256 bf16
  bf16* W1b = W0b + (long)Nn * Dd;
  float* Asum = (float*)(W1b + (long)Nn * Dd);       // 1 MiB each
  float* Vsum = Asum + (long)Bb * NCHUNK * 256;
  float* Hin = Vsum + (long)Bb * NCHUNK * 256;

  const dim3 gemmGrid(Mm / 128, 4);
  const dim3 blk(256);
  const dim3 scanGrid(Bb * NCHUNK);

  // Convert inputs f32 -> bf16
  {
    const long n4x = (long)Mm * Dd / 4;
    cvt_f32_bf16<<<dim3((n4x + 255) / 256), blk, 0, stream>>>(x, Xb, n4x);
    const long n4w = (long)Nn * Dd / 4;
    cvt_f32_bf16<<<dim3((n4w + 255) / 256), blk, 0, stream>>>(W0f, W0b, n4w);
    cvt_f32_bf16<<<dim3((n4w + 255) / 256), blk, 0, stream>>>(W1f, W1b, n4w);
  }

  // Layer 0
  gemm_av<<<gemmGrid, blk, 0, stream>>>(Xb, W0b, b0, AV);
  scan_partial<<<scanGrid, blk, 0, stream>>>(AV, Asum, Vsum);
  scan_combine<<<dim3(Bb), blk, 0, stream>>>(Asum, Vsum, Hin);
  scan_final<true><<<scanGrid, blk, 0, stream>>>(AV, Hin, Xb, nullptr, hlast);

  // Layer 1
  gemm_av<<<gemmGrid, blk, 0, stream>>>(Xb, W1b, b1, AV);
  scan_partial<<<scanGrid, blk, 0, stream>>>(AV, Asum, Vsum);
  scan_combine<<<dim3(Bb), blk, 0, stream>>>(Asum, Vsum, Hin);
  scan_final<false><<<scanGrid, blk, 0, stream>>>(AV, Hin, nullptr, outF,
                                                  hlast + Bb * 256);
}